// Round 1
// baseline (385.109 us; speedup 1.0000x reference)
//
#include <hip/hip_runtime.h>
#include <math.h>

// AmpNorm: x [32,3,384,384] f32, running_amp [3,384,384] f32 (zeros in harness).
// out = real(ifft2( mean_b|fft2(x)| * exp(i*angle(fft2(x))) ))  [f32]
//
// FFT: 384 = 3 * 2^7, Stockham autosort (1 radix-3 stage + 7 radix-2 stages),
// done in LDS with ping-pong buffers, 8 lines per 256-thread block.

#define NFFT   384
#define NL     8          // lines per block
#define LSTR   385        // LDS line stride (float2) — pad to break bank conflicts
#define PLANE  147456     // 384*384
#define IMGS   96         // 32*3
#define GROUPS 48         // 384/NL line-groups per image

__device__ __forceinline__ float2 cmul(float2 a, float2 b) {
    return make_float2(a.x*b.x - a.y*b.y, a.x*b.y + a.y*b.x);
}

__device__ __forceinline__ void fill_tw(float2* tw) {
    for (int k = threadIdx.x; k < NFFT; k += 256) {
        float ang = (-6.28318530717958647692f / (float)NFFT) * (float)k;
        float sv, cv;
        sincosf(ang, &sv, &cv);
        tw[k] = make_float2(cv, sv);   // exp(-2*pi*i*k/384)
    }
}

// Stockham mixed-radix FFT over NL lines resident in LDS.
// DIR = +1 forward (uses table as-is), -1 inverse (conjugate twiddles).
// Data starts in buf0, ends in buf0 (8 stages => even number of swaps).
template<int DIR>
__device__ void fft_lines(float2* buf0, float2* buf1, const float2* tw) {
    const int line = threadIdx.x >> 5;
    const int lane = threadIdx.x & 31;
    float2* src = buf0;
    float2* dst = buf1;

    // ---- radix-3 stage: l=128, m=1 ----
    {
        float2* s = src + line * LSTR;
        float2* d = dst + line * LSTR;
        const float b3 = (DIR > 0) ? -0.86602540378443864676f : 0.86602540378443864676f;
        #pragma unroll
        for (int i = 0; i < 4; ++i) {
            int j = lane + 32 * i;                       // [0,128)
            float2 c0 = s[j], c1 = s[j + 128], c2 = s[j + 256];
            float2 t0 = make_float2(c1.x + c2.x, c1.y + c2.y);
            float2 dd = make_float2(c1.x - c2.x, c1.y - c2.y);
            float2 y0 = make_float2(c0.x + t0.x, c0.y + t0.y);
            float2 u1 = make_float2(c0.x - 0.5f * t0.x, c0.y - 0.5f * t0.y);
            float2 iv = make_float2(-b3 * dd.y, b3 * dd.x);   // i*b3*dd
            float2 y1 = make_float2(u1.x + iv.x, u1.y + iv.y);
            float2 y2 = make_float2(u1.x - iv.x, u1.y - iv.y);
            float2 w1 = tw[j];      w1.y *= (float)DIR;
            float2 w2 = tw[2 * j];  w2.y *= (float)DIR;
            d[3 * j]     = y0;
            d[3 * j + 1] = cmul(w1, y1);
            d[3 * j + 2] = cmul(w2, y2);
        }
    }
    __syncthreads();
    { float2* t = src; src = dst; dst = t; }

    // ---- 7 radix-2 stages: m = 3<<s, l = 64>>s, l*m = 192 always ----
    #pragma unroll
    for (int s7 = 0; s7 < 7; ++s7) {
        const int m = 3 << s7;
        float2* s = src + line * LSTR;
        float2* d = dst + line * LSTR;
        #pragma unroll
        for (int i = 0; i < 6; ++i) {
            int q  = lane + 32 * i;       // [0,192) butterfly id = j*m + k
            int k  = q % m;               // m is constexpr after unroll
            int jm = q - k;               // j*m; twiddle index = j*(384/(2l)) = j*m
            float2 a = s[q];
            float2 b = s[q + 192];
            float2 sum = make_float2(a.x + b.x, a.y + b.y);
            float2 dif = make_float2(a.x - b.x, a.y - b.y);
            float2 w = tw[jm]; w.y *= (float)DIR;
            d[q + jm]     = sum;              // k + 2*j*m
            d[q + jm + m] = cmul(w, dif);     // k + 2*j*m + m
        }
        __syncthreads();
        float2* t = src; src = dst; dst = t;
    }
}

// ---- K1: forward FFT along rows (W axis), real input -> complex A ----
__global__ __launch_bounds__(256) void k_fft_rows_fwd(const float* __restrict__ x,
                                                      float2* __restrict__ A) {
    __shared__ float2 tw[NFFT];
    __shared__ float2 b0[NL * LSTR];
    __shared__ float2 b1[NL * LSTR];
    int bx  = blockIdx.x;
    int img = bx / GROUPS;
    int rg  = bx - img * GROUPS;
    fill_tw(tw);
    int line = threadIdx.x >> 5, lane = threadIdx.x & 31;
    int row  = rg * NL + line;
    const float* xr = x + (size_t)img * PLANE + (size_t)row * NFFT;
    #pragma unroll
    for (int i = 0; i < 12; ++i) {
        int col = lane + 32 * i;
        b0[line * LSTR + col] = make_float2(xr[col], 0.0f);
    }
    __syncthreads();
    fft_lines<1>(b0, b1, tw);
    float2* Ar = A + (size_t)img * PLANE + (size_t)row * NFFT;
    #pragma unroll
    for (int i = 0; i < 12; ++i) {
        int col = lane + 32 * i;
        Ar[col] = b0[line * LSTR + col];
    }
}

// ---- K2: forward FFT along columns (H axis), in place on A ----
__global__ __launch_bounds__(256) void k_fft_cols_fwd(float2* __restrict__ A) {
    __shared__ float2 tw[NFFT];
    __shared__ float2 b0[NL * LSTR];
    __shared__ float2 b1[NL * LSTR];
    int bx  = blockIdx.x;
    int img = bx / GROUPS;
    int cg  = bx - img * GROUPS;
    int w0  = cg * NL;
    fill_tw(tw);
    float2* Ai = A + (size_t)img * PLANE;
    #pragma unroll
    for (int i = 0; i < 12; ++i) {
        int idx = i * 256 + threadIdx.x;
        int h = idx >> 3, wc = idx & 7;
        b0[wc * LSTR + h] = Ai[h * NFFT + w0 + wc];
    }
    __syncthreads();
    fft_lines<1>(b0, b1, tw);
    #pragma unroll
    for (int i = 0; i < 12; ++i) {
        int idx = i * 256 + threadIdx.x;
        int h = idx >> 3, wc = idx & 7;
        Ai[h * NFFT + w0 + wc] = b0[wc * LSTR + h];
    }
}

// ---- K3a/K3b: deterministic sum of running_amp -> flag ----
__global__ __launch_bounds__(256) void k_sum_part(const float* __restrict__ r,
                                                  float* __restrict__ partial) {
    __shared__ float sm[256];
    int t = blockIdx.x * 256 + threadIdx.x;
    sm[threadIdx.x] = r[t];
    __syncthreads();
    for (int s = 128; s > 0; s >>= 1) {
        if (threadIdx.x < s) sm[threadIdx.x] += sm[threadIdx.x + s];
        __syncthreads();
    }
    if (threadIdx.x == 0) partial[blockIdx.x] = sm[0];
}

__global__ __launch_bounds__(256) void k_sum_final(const float* __restrict__ partial,
                                                   float* __restrict__ flag) {
    __shared__ float sm[256];
    float v = 0.0f;
    for (int t = threadIdx.x; t < 1728; t += 256) v += partial[t];
    sm[threadIdx.x] = v;
    __syncthreads();
    for (int s = 128; s > 0; s >>= 1) {
        if (threadIdx.x < s) sm[threadIdx.x] += sm[threadIdx.x + s];
        __syncthreads();
    }
    if (threadIdx.x == 0) flag[0] = sm[0];
}

// ---- K4: batch-mean amplitude ----
__global__ __launch_bounds__(256) void k_amp(const float2* __restrict__ A,
                                             float* __restrict__ amp) {
    int t  = blockIdx.x * 256 + threadIdx.x;   // [0, 3*147456)
    int c  = t / PLANE;
    int hw = t - c * PLANE;
    float s = 0.0f;
    #pragma unroll 4
    for (int b = 0; b < 32; ++b) {
        float2 z = A[(size_t)(b * 3 + c) * PLANE + hw];
        s += sqrtf(z.x * z.x + z.y * z.y);
    }
    amp[t] = s * (1.0f / 32.0f);
}

// ---- K5: scale F <- new_amp * F/|F|, fused into inverse column FFT ----
__global__ __launch_bounds__(256) void k_ifft_cols_scale(float2* __restrict__ A,
                                                         const float* __restrict__ ampm,
                                                         const float* __restrict__ running,
                                                         const float* __restrict__ flag) {
    __shared__ float2 tw[NFFT];
    __shared__ float2 b0[NL * LSTR];
    __shared__ float2 b1[NL * LSTR];
    int bx  = blockIdx.x;
    int img = bx / GROUPS;
    int cg  = bx - img * GROUPS;
    int w0  = cg * NL;
    int c   = img % 3;                 // img = b*3 + c
    fill_tw(tw);
    bool adopt = (flag[0] == 0.0f);
    float2* Ai = A + (size_t)img * PLANE;
    const float* ampc = ampm + (size_t)c * PLANE;
    const float* runc = running + (size_t)c * PLANE;
    #pragma unroll
    for (int i = 0; i < 12; ++i) {
        int idx = i * 256 + threadIdx.x;
        int h = idx >> 3, wc = idx & 7;
        int e = h * NFFT + w0 + wc;
        float2 z  = Ai[e];
        float  am = ampc[e];
        float  na = adopt ? am : (0.9f * runc[e] + 0.1f * am);
        float  mag = sqrtf(z.x * z.x + z.y * z.y);
        float2 zn;
        if (mag > 0.0f) {
            float sc = na / mag;
            zn = make_float2(z.x * sc, z.y * sc);
        } else {
            zn = make_float2(na, 0.0f);   // angle(0)=0 -> exp(i0)=1
        }
        b0[wc * LSTR + h] = zn;
    }
    __syncthreads();
    fft_lines<-1>(b0, b1, tw);
    const float inv = 1.0f / (float)NFFT;
    #pragma unroll
    for (int i = 0; i < 12; ++i) {
        int idx = i * 256 + threadIdx.x;
        int h = idx >> 3, wc = idx & 7;
        float2 z = b0[wc * LSTR + h];
        Ai[h * NFFT + w0 + wc] = make_float2(z.x * inv, z.y * inv);
    }
}

// ---- K6: inverse FFT along rows, write real part ----
__global__ __launch_bounds__(256) void k_ifft_rows_out(const float2* __restrict__ A,
                                                       float* __restrict__ out) {
    __shared__ float2 tw[NFFT];
    __shared__ float2 b0[NL * LSTR];
    __shared__ float2 b1[NL * LSTR];
    int bx  = blockIdx.x;
    int img = bx / GROUPS;
    int rg  = bx - img * GROUPS;
    fill_tw(tw);
    int line = threadIdx.x >> 5, lane = threadIdx.x & 31;
    int row  = rg * NL + line;
    const float2* Ar = A + (size_t)img * PLANE + (size_t)row * NFFT;
    #pragma unroll
    for (int i = 0; i < 12; ++i) {
        int col = lane + 32 * i;
        b0[line * LSTR + col] = Ar[col];
    }
    __syncthreads();
    fft_lines<-1>(b0, b1, tw);
    const float inv = 1.0f / (float)NFFT;
    float* outr = out + (size_t)img * PLANE + (size_t)row * NFFT;
    #pragma unroll
    for (int i = 0; i < 12; ++i) {
        int col = lane + 32 * i;
        outr[col] = b0[line * LSTR + col].x * inv;
    }
}

extern "C" void kernel_launch(void* const* d_in, const int* in_sizes, int n_in,
                              void* d_out, int out_size, void* d_ws, size_t ws_size,
                              hipStream_t stream) {
    const float* x       = (const float*)d_in[0];     // [32,3,384,384]
    const float* running = (const float*)d_in[1];     // [3,384,384]
    float* out = (float*)d_out;

    char* ws = (char*)d_ws;
    float2* A    = (float2*)ws;                                   // 96*147456*8 = 113246208 B
    float*  ampm = (float*)(ws + 113246208);                      // 442368*4 = 1769472 B
    float*  part = (float*)(ws + 113246208 + 1769472);            // 1728*4 B
    float*  flag = (float*)(ws + 113246208 + 1769472 + 8192);     // 4 B

    k_sum_part<<<1728, 256, 0, stream>>>(running, part);
    k_sum_final<<<1, 256, 0, stream>>>(part, flag);
    k_fft_rows_fwd<<<IMGS * GROUPS, 256, 0, stream>>>(x, A);
    k_fft_cols_fwd<<<IMGS * GROUPS, 256, 0, stream>>>(A);
    k_amp<<<1728, 256, 0, stream>>>(A, ampm);
    k_ifft_cols_scale<<<IMGS * GROUPS, 256, 0, stream>>>(A, ampm, running, flag);
    k_ifft_rows_out<<<IMGS * GROUPS, 256, 0, stream>>>(A, out);
}

// Round 2
// 234.338 us; speedup vs baseline: 1.6434x; 1.6434x over previous
//
#include <hip/hip_runtime.h>
#include <math.h>

// AmpNorm via real-input 2D FFT (half spectrum) on MI355X.
// x [32,3,384,384] f32; running_amp [3,384,384] f32 (all-zero in bench -> adopt branch).
// Half spectrum A: [96][384][PADW=200] complex (w=0..192 valid, 193..199 zero).
// FFT: 384 = 3*4*4*4*2 Stockham (radix 3,4,4,4,2), LDS ping-pong, 8 lines/block.

#define NFFT   384
#define NL     8
#define LSTR   385        // LDS line stride in float2
#define PADW   200        // padded half-spectrum width (193 valid)
#define PLANE  147456     // 384*384
#define IMGS   96

__device__ __forceinline__ float2 cmul(float2 a, float2 b) {
    return make_float2(a.x*b.x - a.y*b.y, a.x*b.y + a.y*b.x);
}

__device__ __forceinline__ void fill_tw(float2* tw) {
    for (int k = threadIdx.x; k < NFFT; k += 256) {
        float ang = (-6.28318530717958647692f / (float)NFFT) * (float)k;
        float sv, cv;
        sincosf(ang, &sv, &cv);
        tw[k] = make_float2(cv, sv);   // exp(-2*pi*i*k/384)
    }
}

// Stockham FFT over NL lines in LDS. Stages: r3(m=1), r4(m=3), r4(m=12), r4(m=48), r2(m=192).
// DIR=+1 fwd, -1 inv (conjugated twiddles). Returns buffer holding the result (buf1: 5 swaps).
template<int DIR>
__device__ float2* fft_lines(float2* buf0, float2* buf1, const float2* tw) {
    const int line = threadIdx.x >> 5;
    const int lane = threadIdx.x & 31;
    const float dir = (float)DIR;
    float2* src = buf0;
    float2* dst = buf1;

    // ---- radix-3, m=1: 128 butterflies/line ----
    {
        float2* s = src + line * LSTR;
        float2* d = dst + line * LSTR;
        const float b3 = (DIR > 0) ? -0.86602540378443864676f : 0.86602540378443864676f;
        #pragma unroll
        for (int i = 0; i < 4; ++i) {
            int j = lane + 32 * i;                       // [0,128)
            float2 c0 = s[j], c1 = s[j + 128], c2 = s[j + 256];
            float2 t0 = make_float2(c1.x + c2.x, c1.y + c2.y);
            float2 dd = make_float2(c1.x - c2.x, c1.y - c2.y);
            float2 y0 = make_float2(c0.x + t0.x, c0.y + t0.y);
            float2 u1 = make_float2(c0.x - 0.5f * t0.x, c0.y - 0.5f * t0.y);
            float2 iv = make_float2(-b3 * dd.y, b3 * dd.x);
            float2 y1 = make_float2(u1.x + iv.x, u1.y + iv.y);
            float2 y2 = make_float2(u1.x - iv.x, u1.y - iv.y);
            float2 w1 = tw[j];      w1.y *= dir;
            float2 w2 = tw[2 * j];  w2.y *= dir;
            d[3 * j]     = y0;
            d[3 * j + 1] = cmul(w1, y1);
            d[3 * j + 2] = cmul(w2, y2);
        }
    }
    __syncthreads();
    { float2* t = src; src = dst; dst = t; }

    // ---- radix-4 stages: m = 3, 12, 48; 96 butterflies/line each ----
    #pragma unroll
    for (int st = 0; st < 3; ++st) {
        const int m = 3 << (2 * st);
        float2* s = src + line * LSTR;
        float2* d = dst + line * LSTR;
        #pragma unroll
        for (int i = 0; i < 3; ++i) {
            int q  = lane + 32 * i;          // [0,96) = j*m + k
            int k  = q % m;
            int jm = q - k;
            float2 a = s[q], b = s[q + 96], c = s[q + 192], e = s[q + 288];
            float2 acp = make_float2(a.x + c.x, a.y + c.y);
            float2 acm = make_float2(a.x - c.x, a.y - c.y);
            float2 bdp = make_float2(b.x + e.x, b.y + e.y);
            float2 bdm = make_float2(b.x - e.x, b.y - e.y);
            float2 ibd = make_float2(-dir * bdm.y, dir * bdm.x);  // i*DIR*(b-d)
            float2 y0 = make_float2(acp.x + bdp.x, acp.y + bdp.y);
            float2 y2 = make_float2(acp.x - bdp.x, acp.y - bdp.y);
            float2 y1 = make_float2(acm.x - ibd.x, acm.y - ibd.y);
            float2 y3 = make_float2(acm.x + ibd.x, acm.y + ibd.y);
            float2 w1 = tw[jm];      w1.y *= dir;
            float2 w2 = tw[2 * jm];  w2.y *= dir;
            float2 w3 = tw[3 * jm];  w3.y *= dir;
            d[4 * jm + k]         = y0;
            d[4 * jm + k + m]     = cmul(w1, y1);
            d[4 * jm + k + 2 * m] = cmul(w2, y2);
            d[4 * jm + k + 3 * m] = cmul(w3, y3);
        }
        __syncthreads();
        float2* t = src; src = dst; dst = t;
    }

    // ---- radix-2, m=192: j=0 always -> twiddle-free ----
    {
        float2* s = src + line * LSTR;
        float2* d = dst + line * LSTR;
        #pragma unroll
        for (int i = 0; i < 6; ++i) {
            int q = lane + 32 * i;           // [0,192)
            float2 a = s[q];
            float2 b = s[q + 192];
            d[q]       = make_float2(a.x + b.x, a.y + b.y);
            d[q + 192] = make_float2(a.x - b.x, a.y - b.y);
        }
        __syncthreads();
        float2* t = src; src = dst; dst = t;
    }
    return src;
}

// ---- K1: forward row FFT, two real rows packed per complex FFT; write half spectrum ----
__global__ __launch_bounds__(256) void k_fft_rows_fwd(const float* __restrict__ x,
                                                      float2* __restrict__ A) {
    __shared__ float2 tw[NFFT];
    __shared__ float2 b0[NL * LSTR];
    __shared__ float2 b1[NL * LSTR];
    int bx  = blockIdx.x;
    int img = bx / 24;
    int rg  = bx - img * 24;
    fill_tw(tw);
    int line = threadIdx.x >> 5, lane = threadIdx.x & 31;
    int pr   = rg * NL + line;              // row-pair index [0,192)
    const float* xa = x + (size_t)img * PLANE + (size_t)(2 * pr) * NFFT;
    const float* xb = xa + NFFT;
    #pragma unroll
    for (int i = 0; i < 12; ++i) {
        int col = lane + 32 * i;
        b0[line * LSTR + col] = make_float2(xa[col], xb[col]);
    }
    __syncthreads();
    float2* R = fft_lines<1>(b0, b1, tw);
    float2* s = R + line * LSTR;
    float2* Aa = A + ((size_t)img * NFFT + 2 * pr) * PADW;
    float2* Ab = Aa + PADW;
    #pragma unroll
    for (int i = 0; i < 7; ++i) {
        int w = lane + 32 * i;
        if (w <= 192) {
            float2 Z  = s[w];
            float2 Zm = s[w == 0 ? 0 : NFFT - w];
            float2 Fa = make_float2(0.5f * (Z.x + Zm.x), 0.5f * (Z.y - Zm.y));
            float2 Fb = make_float2(0.5f * (Z.y + Zm.y), -0.5f * (Z.x - Zm.x));
            Aa[w] = Fa;
            Ab[w] = Fb;
        }
    }
    if (lane < 7) {   // zero the pad columns
        Aa[193 + lane] = make_float2(0.0f, 0.0f);
        Ab[193 + lane] = make_float2(0.0f, 0.0f);
    }
}

// ---- K2: forward column FFT on half spectrum, in place ----
__global__ __launch_bounds__(256) void k_fft_cols_fwd(float2* __restrict__ A) {
    __shared__ float2 tw[NFFT];
    __shared__ float2 b0[NL * LSTR];
    __shared__ float2 b1[NL * LSTR];
    int bx  = blockIdx.x;
    int img = bx / 25;
    int cg  = bx - img * 25;
    int w0  = cg * NL;
    fill_tw(tw);
    float2* Ai = A + (size_t)img * NFFT * PADW;
    #pragma unroll
    for (int i = 0; i < 12; ++i) {
        int idx = i * 256 + threadIdx.x;
        int h = idx >> 3, wc = idx & 7;
        b0[wc * LSTR + h] = Ai[h * PADW + w0 + wc];
    }
    __syncthreads();
    float2* R = fft_lines<1>(b0, b1, tw);
    #pragma unroll
    for (int i = 0; i < 12; ++i) {
        int idx = i * 256 + threadIdx.x;
        int h = idx >> 3, wc = idx & 7;
        Ai[h * PADW + w0 + wc] = R[wc * LSTR + h];
    }
}

// ---- K3: deterministic sum of running_amp -> flag ----
__global__ __launch_bounds__(256) void k_sum_part(const float* __restrict__ r,
                                                  float* __restrict__ partial) {
    __shared__ float sm[256];
    int t = blockIdx.x * 256 + threadIdx.x;
    sm[threadIdx.x] = r[t];
    __syncthreads();
    for (int s = 128; s > 0; s >>= 1) {
        if (threadIdx.x < s) sm[threadIdx.x] += sm[threadIdx.x + s];
        __syncthreads();
    }
    if (threadIdx.x == 0) partial[blockIdx.x] = sm[0];
}

__global__ __launch_bounds__(256) void k_sum_final(const float* __restrict__ partial,
                                                   float* __restrict__ flag) {
    __shared__ float sm[256];
    float v = 0.0f;
    for (int t = threadIdx.x; t < 1728; t += 256) v += partial[t];
    sm[threadIdx.x] = v;
    __syncthreads();
    for (int s = 128; s > 0; s >>= 1) {
        if (threadIdx.x < s) sm[threadIdx.x] += sm[threadIdx.x + s];
        __syncthreads();
    }
    if (threadIdx.x == 0) flag[0] = sm[0];
}

// ---- K4: batch-mean amplitude on half spectrum; one (c,h) row per block ----
__global__ __launch_bounds__(256) void k_amp(const float2* __restrict__ A,
                                             float* __restrict__ amp) {
    int c = blockIdx.x / NFFT;
    int h = blockIdx.x - c * NFFT;
    int w = threadIdx.x;
    if (w >= 193) return;
    float s = 0.0f;
    #pragma unroll 4
    for (int b = 0; b < 32; ++b) {
        float2 z = A[((size_t)(b * 3 + c) * NFFT + h) * PADW + w];
        s += sqrtf(z.x * z.x + z.y * z.y);
    }
    amp[((size_t)c * NFFT + h) * PADW + w] = s * (1.0f / 32.0f);
}

// ---- K5: scale F <- new_amp * F/|F|, fused into inverse column FFT ----
__global__ __launch_bounds__(256) void k_ifft_cols_scale(float2* __restrict__ A,
                                                         const float* __restrict__ ampm,
                                                         const float* __restrict__ running,
                                                         const float* __restrict__ flag) {
    __shared__ float2 tw[NFFT];
    __shared__ float2 b0[NL * LSTR];
    __shared__ float2 b1[NL * LSTR];
    int bx  = blockIdx.x;
    int img = bx / 25;
    int cg  = bx - img * 25;
    int w0  = cg * NL;
    int c   = img % 3;
    fill_tw(tw);
    bool adopt = (flag[0] == 0.0f);
    float2* Ai = A + (size_t)img * NFFT * PADW;
    #pragma unroll
    for (int i = 0; i < 12; ++i) {
        int idx = i * 256 + threadIdx.x;
        int h = idx >> 3, wc = idx & 7;
        int w = w0 + wc;
        float2 z  = Ai[h * PADW + w];
        float  am = ampm[((size_t)c * NFFT + h) * PADW + w];
        float  na;
        if (adopt) na = am;
        else {
            int wr = (w < NFFT) ? w : 0;   // EMA branch never taken in bench (running==0)
            na = 0.9f * running[((size_t)c * NFFT + h) * NFFT + wr] + 0.1f * am;
        }
        float mag = sqrtf(z.x * z.x + z.y * z.y);
        float2 zn;
        if (mag > 0.0f) {
            float sc = na / mag;
            zn = make_float2(z.x * sc, z.y * sc);
        } else {
            zn = make_float2(na, 0.0f);
        }
        b0[wc * LSTR + h] = zn;
    }
    __syncthreads();
    float2* R = fft_lines<-1>(b0, b1, tw);
    const float inv = 1.0f / (float)NFFT;
    #pragma unroll
    for (int i = 0; i < 12; ++i) {
        int idx = i * 256 + threadIdx.x;
        int h = idx >> 3, wc = idx & 7;
        float2 z = R[wc * LSTR + h];
        Ai[h * PADW + w0 + wc] = make_float2(z.x * inv, z.y * inv);
    }
}

// ---- K6: inverse row FFT (C2R), two real rows per complex FFT ----
__global__ __launch_bounds__(256) void k_ifft_rows_out(const float2* __restrict__ A,
                                                       float* __restrict__ out) {
    __shared__ float2 tw[NFFT];
    __shared__ float2 b0[NL * LSTR];
    __shared__ float2 b1[NL * LSTR];
    int bx  = blockIdx.x;
    int img = bx / 24;
    int rg  = bx - img * 24;
    fill_tw(tw);
    int line = threadIdx.x >> 5, lane = threadIdx.x & 31;
    int pr   = rg * NL + line;
    const float2* Aa = A + ((size_t)img * NFFT + 2 * pr) * PADW;
    const float2* Ab = Aa + PADW;
    float2* s = b0 + line * LSTR;
    #pragma unroll
    for (int i = 0; i < 7; ++i) {
        int w = lane + 32 * i;
        if (w <= 192) {
            float2 Fa = Aa[w];
            float2 Fb = Ab[w];
            s[w] = make_float2(Fa.x - Fb.y, Fa.y + Fb.x);          // Z(w) = Fa + i*Fb
            if (w >= 1 && w <= 191)
                s[NFFT - w] = make_float2(Fa.x + Fb.y, Fb.x - Fa.y); // conj(Fa) + i*conj(Fb)
        }
    }
    __syncthreads();
    float2* R = fft_lines<-1>(b0, b1, tw);
    float2* rs = R + line * LSTR;
    const float inv = 1.0f / (float)NFFT;
    float* oa = out + (size_t)img * PLANE + (size_t)(2 * pr) * NFFT;
    float* ob = oa + NFFT;
    #pragma unroll
    for (int i = 0; i < 12; ++i) {
        int col = lane + 32 * i;
        float2 z = rs[col];
        oa[col] = z.x * inv;
        ob[col] = z.y * inv;
    }
}

extern "C" void kernel_launch(void* const* d_in, const int* in_sizes, int n_in,
                              void* d_out, int out_size, void* d_ws, size_t ws_size,
                              hipStream_t stream) {
    const float* x       = (const float*)d_in[0];
    const float* running = (const float*)d_in[1];
    float* out = (float*)d_out;

    char* ws = (char*)d_ws;
    float2* A    = (float2*)ws;                         // 96*384*200*8 = 58,982,400 B
    float*  ampm = (float*)(ws + 58982400);             // 3*384*200*4 = 921,600 B
    float*  part = (float*)(ws + 58982400 + 921600);    // 1728*4 B
    float*  flag = (float*)(ws + 58982400 + 921600 + 8192);

    k_sum_part<<<1728, 256, 0, stream>>>(running, part);
    k_sum_final<<<1, 256, 0, stream>>>(part, flag);
    k_fft_rows_fwd<<<IMGS * 24, 256, 0, stream>>>(x, A);
    k_fft_cols_fwd<<<IMGS * 25, 256, 0, stream>>>(A);
    k_amp<<<3 * NFFT, 256, 0, stream>>>(A, ampm);
    k_ifft_cols_scale<<<IMGS * 25, 256, 0, stream>>>(A, ampm, running, flag);
    k_ifft_rows_out<<<IMGS * 24, 256, 0, stream>>>(A, out);
}